// Round 2
// baseline (491.863 us; speedup 1.0000x reference)
//
#include <hip/hip_runtime.h>
#include <hip/hip_bf16.h>
#include <math.h>

#define IMG 256

__device__ __forceinline__ unsigned int bf16u(float f) {
    __hip_bfloat16 h = __float2bfloat16(f);
    unsigned short s;
    __builtin_memcpy(&s, &h, 2);
    return (unsigned int)s;
}
__device__ __forceinline__ float bflo(unsigned int v) { return __uint_as_float(v << 16); }
__device__ __forceinline__ float bfhi(unsigned int v) { return __uint_as_float(v & 0xffff0000u); }

// ---------------- Kernel 1: gating conv 7x7 stride 4 + relu + partial sums -----
// grid (16 tiles = 8 row x 2 col, 64 batch), 256 threads
__global__ __launch_bounds__(256) void gate_conv_kernel(
    const float* __restrict__ x, const float* __restrict__ Wg,
    float* __restrict__ partials)
{
    __shared__ float xs[35 * 132];      // input rows 32*rt-1.., cols 128*ct-1..
    __shared__ float wshT[49 * 64];     // wshT[k][gf]

    const int tile = blockIdx.x;        // 0..15
    const int rt = tile >> 1, ct = tile & 1;
    const int b  = blockIdx.y;
    const int tid = threadIdx.x;

    for (int i = tid; i < 49 * 64; i += 256) {
        int k = i >> 6, gf = i & 63;
        wshT[i] = Wg[gf * 49 + k];
    }
    const float* xb = x + (size_t)b * (IMG * IMG);
    const int iy0 = rt * 32 - 1;
    const int ix0 = ct * 128 - 1;
    for (int i = tid; i < 35 * 132; i += 256) {
        int r = i / 132, c = i - r * 132;
        int iy = iy0 + r, ix = ix0 + c;
        float v = 0.f;
        if (iy >= 0 && iy < IMG && ix >= 0 && ix < IMG) v = xb[iy * IMG + ix];
        xs[i] = v;
    }
    __syncthreads();

    const int gf4   = tid >> 4;   // 0..15 -> gf = gf4*4+g
    const int pslot = tid & 15;   // 0..15 -> out col = pslot + 16*p (tile-local)

    float rsum[4] = {0.f, 0.f, 0.f, 0.f};

    for (int pgb = 0; pgb < 2; ++pgb) {      // output rows r = pgb*4 + q
        float acc[4][4][2];
        #pragma unroll
        for (int g = 0; g < 4; ++g)
            #pragma unroll
            for (int q = 0; q < 4; ++q)
                #pragma unroll
                for (int p = 0; p < 2; ++p) acc[g][q][p] = 0.f;

        for (int ky = 0; ky < 7; ++ky) {
            float4 wk[7];
            #pragma unroll
            for (int kx = 0; kx < 7; ++kx)
                wk[kx] = *(const float4*)&wshT[(ky * 7 + kx) * 64 + (gf4 << 2)];
            #pragma unroll
            for (int q = 0; q < 4; ++q) {
                const int row = (pgb * 4 + q) * 4 + ky;
                #pragma unroll
                for (int p = 0; p < 2; ++p) {
                    const float* xr = &xs[row * 132 + (pslot << 2) + (p << 6)];
                    const float4 xa = *(const float4*)xr;
                    const float4 xb4 = *(const float4*)(xr + 4);
                    const float xv[7] = {xa.x, xa.y, xa.z, xa.w, xb4.x, xb4.y, xb4.z};
                    #pragma unroll
                    for (int kx = 0; kx < 7; ++kx) {
                        acc[0][q][p] += wk[kx].x * xv[kx];
                        acc[1][q][p] += wk[kx].y * xv[kx];
                        acc[2][q][p] += wk[kx].z * xv[kx];
                        acc[3][q][p] += wk[kx].w * xv[kx];
                    }
                }
            }
        }
        #pragma unroll
        for (int g = 0; g < 4; ++g)
            #pragma unroll
            for (int q = 0; q < 4; ++q)
                #pragma unroll
                for (int p = 0; p < 2; ++p)
                    rsum[g] += fmaxf(acc[g][q][p], 0.f);
    }

    #pragma unroll
    for (int g = 0; g < 4; ++g) {
        float v = rsum[g];
        v += __shfl_xor(v, 8);
        v += __shfl_xor(v, 4);
        v += __shfl_xor(v, 2);
        v += __shfl_xor(v, 1);
        if (pslot == 0)
            partials[((b * 16 + tile) * 64) + (gf4 << 2) + g] = v;
    }
}

// ---------------- Kernel 2: gating finalize (feats -> heads -> weights) --------
__global__ void gate_finalize_kernel(
    const float* __restrict__ partials,
    const float* __restrict__ Wc, const float* __restrict__ bc,
    const float* __restrict__ Wp, const float* __restrict__ bp,
    int* __restrict__ gidx, float* __restrict__ gw)
{
    const int b = threadIdx.x;   // 64 threads
    float f[64];
    #pragma unroll
    for (int g = 0; g < 64; ++g) f[g] = 0.f;
    const float* pb = partials + b * 1024;   // 16 tiles x 64 gf, contiguous
    #pragma unroll
    for (int t = 0; t < 16; ++t)
        #pragma unroll
        for (int g4 = 0; g4 < 16; ++g4) {
            const float4 v = *(const float4*)&pb[t * 64 + (g4 << 2)];
            f[(g4 << 2) + 0] += v.x;
            f[(g4 << 2) + 1] += v.y;
            f[(g4 << 2) + 2] += v.z;
            f[(g4 << 2) + 3] += v.w;
        }
    #pragma unroll
    for (int g = 0; g < 64; ++g) f[g] *= (1.0f / 4096.0f);

    float cl[6], pl[2];
    #pragma unroll
    for (int j = 0; j < 6; ++j) {
        float s = bc[j];
        #pragma unroll
        for (int g = 0; g < 64; ++g) s += f[g] * Wc[j * 64 + g];
        cl[j] = s;
    }
    #pragma unroll
    for (int j = 0; j < 2; ++j) {
        float s = bp[j];
        #pragma unroll
        for (int g = 0; g < 64; ++g) s += f[g] * Wp[j * 64 + g];
        pl[j] = s;
    }
    const float pm = fmaxf(pl[0], pl[1]);
    const float e0 = expf(pl[0] - pm), e1 = expf(pl[1] - pm);
    const int   pi = (pl[1] > pl[0]) ? 1 : 0;
    const float pv = fmaxf(e0, e1) / (e0 + e1);
    float cm = cl[0];
    #pragma unroll
    for (int j = 1; j < 6; ++j) cm = fmaxf(cm, cl[j]);
    float es = 0.f, ce[6];
    #pragma unroll
    for (int j = 0; j < 6; ++j) { ce[j] = expf(cl[j] - cm); es += ce[j]; }
    int ci = 0; float cbest = cl[0];
    #pragma unroll
    for (int j = 1; j < 6; ++j) if (cl[j] > cbest) { cbest = cl[j]; ci = j; }
    const float cv = ce[ci] / es;

    const float wp = 0.3f * pv;
    const float wc = 0.7f * cv;
    const float tot = wp + wc + 1e-8f;
    gidx[b]      = pi;
    gidx[64 + b] = ci + 2;
    gw[b]        = wp / tot;
    gw[64 + b]   = wc / tot;
}

// ---------------- Kernel 3: fused two-expert conv3x3 -> relu -> conv3x3 -------
// grid (64 tiles of 32x32, 64 batch), 256 threads
__global__ __launch_bounds__(256) void expert_kernel(
    const float* __restrict__ x,
    const float* __restrict__ We1, const float* __restrict__ be1,
    const float* __restrict__ We2, const float* __restrict__ be2,
    const int* __restrict__ gidx, const float* __restrict__ gw,
    float* __restrict__ out)
{
    __shared__ float xs[36 * 40];                       // fp32 x tile + halo2
    __shared__ __align__(16) unsigned short hs[8 * 34 * 36];  // bf16 h tile + halo1

    const int tile = blockIdx.x;
    const int b    = blockIdx.y;
    const int ty = tile >> 3, tx = tile & 7;
    const int y0 = ty * 32, x0 = tx * 32;
    const int tid = threadIdx.x;
    const bool interior = (ty != 0) && (ty != 7) && (tx != 0) && (tx != 7);

    const float* xb = x + (size_t)b * (IMG * IMG);
    if (interior) {
        for (int i = tid; i < 36 * 40; i += 256) {
            int r = i / 40, c = i - r * 40;
            xs[i] = xb[(y0 - 2 + r) * IMG + (x0 - 2 + c)];
        }
    } else {
        for (int i = tid; i < 36 * 40; i += 256) {
            int r = i / 40, c = i - r * 40;
            float v = 0.f;
            if (c < 36) {
                int gy = y0 - 2 + r, gx = x0 - 2 + c;
                if (gy >= 0 && gy < IMG && gx >= 0 && gx < IMG) v = xb[gy * IMG + gx];
            }
            xs[i] = v;
        }
    }

    const int ep = __builtin_amdgcn_readfirstlane(gidx[b]);
    const int ec = __builtin_amdgcn_readfirstlane(gidx[64 + b]);
    const float wA = __uint_as_float(__builtin_amdgcn_readfirstlane(__float_as_uint(gw[b])));
    const float wB = __uint_as_float(__builtin_amdgcn_readfirstlane(__float_as_uint(gw[64 + b])));

    const int r_ = tid >> 3;          // 0..31 output row
    const int c0 = (tid & 7) << 2;    // output col group (4 cols)
    const int c1ch   = tid >> 5;      // conv1: channel 0..7
    const int lane32 = tid & 31;

    float oacc0 = 0.f, oacc1 = 0.f, oacc2 = 0.f, oacc3 = 0.f;

    __syncthreads();

    for (int ei = 0; ei < 2; ++ei) {
        const int   e   = ei ? ec : ep;
        const float wgt = ei ? wB : wA;

        float w1r[9];
        const float* w1p = We1 + e * 72 + c1ch * 9;
        #pragma unroll
        for (int k = 0; k < 9; ++k) w1r[k] = w1p[k];
        const float b1r = be1[e * 8 + c1ch];

        if (ei) __syncthreads();   // prev conv2 reads done before hs overwrite

        // ---- conv1: h = relu(conv(x) + b1) in bf16, zero outside image ----
        if (interior) {
            for (int j = lane32; j < 306; j += 32) {
                const int hy = j / 9;
                const int cb = (j - hy * 9) << 2;     // 0,4,...,32
                float a0 = b1r, a1 = b1r, a2 = b1r, a3 = b1r;
                #pragma unroll
                for (int ky = 0; ky < 3; ++ky) {
                    const float* xr = &xs[(hy + ky) * 40 + cb];
                    const float2 xa  = *(const float2*)(xr);
                    const float2 xb2 = *(const float2*)(xr + 2);
                    const float2 xc2 = *(const float2*)(xr + 4);
                    const float wa = w1r[ky * 3 + 0], wb = w1r[ky * 3 + 1], wcc = w1r[ky * 3 + 2];
                    a0 += wa * xa.x  + wb * xa.y  + wcc * xb2.x;
                    a1 += wa * xa.y  + wb * xb2.x + wcc * xb2.y;
                    a2 += wa * xb2.x + wb * xb2.y + wcc * xc2.x;
                    a3 += wa * xb2.y + wb * xc2.x + wcc * xc2.y;
                }
                const unsigned int lo = bf16u(fmaxf(a0, 0.f)) | (bf16u(fmaxf(a1, 0.f)) << 16);
                const unsigned int hi = bf16u(fmaxf(a2, 0.f)) | (bf16u(fmaxf(a3, 0.f)) << 16);
                unsigned short* hp = &hs[c1ch * 1224 + hy * 36 + cb];
                if (cb < 32) *(uint2*)hp = make_uint2(lo, hi);
                else         *(unsigned int*)hp = lo;
            }
        } else {
            for (int j = lane32; j < 306; j += 32) {
                const int hy = j / 9;
                const int cb = (j - hy * 9) << 2;
                float a0 = b1r, a1 = b1r, a2 = b1r, a3 = b1r;
                #pragma unroll
                for (int ky = 0; ky < 3; ++ky) {
                    const float* xr = &xs[(hy + ky) * 40 + cb];
                    const float2 xa  = *(const float2*)(xr);
                    const float2 xb2 = *(const float2*)(xr + 2);
                    const float2 xc2 = *(const float2*)(xr + 4);
                    const float wa = w1r[ky * 3 + 0], wb = w1r[ky * 3 + 1], wcc = w1r[ky * 3 + 2];
                    a0 += wa * xa.x  + wb * xa.y  + wcc * xb2.x;
                    a1 += wa * xa.y  + wb * xb2.x + wcc * xb2.y;
                    a2 += wa * xb2.x + wb * xb2.y + wcc * xc2.x;
                    a3 += wa * xb2.y + wb * xc2.x + wcc * xc2.y;
                }
                const int gy = y0 - 1 + hy;
                const int gx = x0 - 1 + cb;
                const bool rowok = (gy >= 0) && (gy < IMG);
                const float h0 = (rowok && gx >= 0 && gx < IMG) ? fmaxf(a0, 0.f) : 0.f;
                const float h1 = (rowok && (gx + 1) < IMG)      ? fmaxf(a1, 0.f) : 0.f;
                const float h2 = (rowok && (gx + 2) < IMG)      ? fmaxf(a2, 0.f) : 0.f;
                const float h3 = (rowok && (gx + 3) < IMG)      ? fmaxf(a3, 0.f) : 0.f;
                const unsigned int lo = bf16u(h0) | (bf16u(h1) << 16);
                const unsigned int hi = bf16u(h2) | (bf16u(h3) << 16);
                unsigned short* hp = &hs[c1ch * 1224 + hy * 36 + cb];
                if (cb < 32) *(uint2*)hp = make_uint2(lo, hi);
                else         *(unsigned int*)hp = lo;
            }
        }
        __syncthreads();

        // ---- conv2: y = conv(h) + b2, accumulate with gate weight ----
        float a0 = 0.f, a1 = 0.f, a2 = 0.f, a3 = 0.f;
        #pragma unroll
        for (int ch = 0; ch < 8; ++ch) {
            const float* w2p = We2 + e * 72 + ch * 9;   // e uniform -> s_load
            float w2r[9];
            #pragma unroll
            for (int k = 0; k < 9; ++k) w2r[k] = w2p[k];
            #pragma unroll
            for (int ky = 0; ky < 3; ++ky) {
                const unsigned short* hp = &hs[ch * 1224 + (r_ + ky) * 36 + c0];
                const uint2 q4 = *(const uint2*)hp;
                const unsigned int q2 = *(const unsigned int*)(hp + 4);
                const float h0 = bflo(q4.x), h1 = bfhi(q4.x);
                const float h2 = bflo(q4.y), h3 = bfhi(q4.y);
                const float h4 = bflo(q2),   h5 = bfhi(q2);
                const float wa = w2r[ky * 3], wb = w2r[ky * 3 + 1], wcx = w2r[ky * 3 + 2];
                a0 += wa * h0 + wb * h1 + wcx * h2;
                a1 += wa * h1 + wb * h2 + wcx * h3;
                a2 += wa * h2 + wb * h3 + wcx * h4;
                a3 += wa * h3 + wb * h4 + wcx * h5;
            }
        }
        const float b2v = be2[e];
        oacc0 += wgt * (a0 + b2v);
        oacc1 += wgt * (a1 + b2v);
        oacc2 += wgt * (a2 + b2v);
        oacc3 += wgt * (a3 + b2v);
    }

    const float4 o4 = make_float4(oacc0, oacc1, oacc2, oacc3);
    *(float4*)&out[(size_t)b * (IMG * IMG) + (y0 + r_) * IMG + (x0 + c0)] = o4;
}

extern "C" void kernel_launch(void* const* d_in, const int* in_sizes, int n_in,
                              void* d_out, int out_size, void* d_ws, size_t ws_size,
                              hipStream_t stream) {
    const float* x   = (const float*)d_in[0];
    const float* Wg  = (const float*)d_in[1];
    const float* Wc  = (const float*)d_in[2];
    const float* bc  = (const float*)d_in[3];
    const float* Wp  = (const float*)d_in[4];
    const float* bp  = (const float*)d_in[5];
    const float* We1 = (const float*)d_in[6];
    const float* be1 = (const float*)d_in[7];
    const float* We2 = (const float*)d_in[8];
    const float* be2 = (const float*)d_in[9];
    float* out = (float*)d_out;

    float* partials = (float*)d_ws;                              // 64*16*64 floats = 256 KB
    int*   gidx     = (int*)((char*)d_ws + 262144);              // 128 ints
    float* gw       = (float*)((char*)d_ws + 262144 + 512);      // 128 floats

    gate_conv_kernel<<<dim3(16, 64), dim3(256), 0, stream>>>(x, Wg, partials);
    gate_finalize_kernel<<<dim3(1), dim3(64), 0, stream>>>(partials, Wc, bc, Wp, bp, gidx, gw);
    expert_kernel<<<dim3(64, 64), dim3(256), 0, stream>>>(x, We1, be1, We2, be2, gidx, gw, out);
}

// Round 3
// 129.636 us; speedup vs baseline: 3.7942x; 3.7942x over previous
//
#include <hip/hip_runtime.h>
#include <hip/hip_bf16.h>
#include <math.h>

#define IMG 256

__device__ __forceinline__ unsigned int bf16u(float f) {
    __hip_bfloat16 h = __float2bfloat16(f);
    unsigned short s;
    __builtin_memcpy(&s, &h, 2);
    return (unsigned int)s;
}
__device__ __forceinline__ float bflo(unsigned int v) { return __uint_as_float(v << 16); }
__device__ __forceinline__ float bfhi(unsigned int v) { return __uint_as_float(v & 0xffff0000u); }

// ---------------- Kernel 1: gating conv 7x7 stride 4 + relu + partial sums -----
// grid (16 tiles = 8 row x 2 col, 64 batch), 256 threads
__global__ __launch_bounds__(256) void gate_conv_kernel(
    const float* __restrict__ x, const float* __restrict__ Wg,
    float* __restrict__ partials)
{
    __shared__ float xs[35 * 132];      // input rows 32*rt-1.., cols 128*ct-1..
    __shared__ float wshT[49 * 64];     // wshT[k][gf]

    const int tile = blockIdx.x;        // 0..15
    const int rt = tile >> 1, ct = tile & 1;
    const int b  = blockIdx.y;
    const int tid = threadIdx.x;

    for (int i = tid; i < 49 * 64; i += 256) {
        int k = i >> 6, gf = i & 63;
        wshT[i] = Wg[gf * 49 + k];
    }
    const float* xb = x + (size_t)b * (IMG * IMG);
    const int iy0 = rt * 32 - 1;
    const int ix0 = ct * 128 - 1;
    for (int i = tid; i < 35 * 132; i += 256) {
        int r = i / 132, c = i - r * 132;
        int iy = iy0 + r, ix = ix0 + c;
        float v = 0.f;
        if (iy >= 0 && iy < IMG && ix >= 0 && ix < IMG) v = xb[iy * IMG + ix];
        xs[i] = v;
    }
    __syncthreads();

    const int gf4   = tid >> 4;   // 0..15 -> gf = gf4*4+g
    const int pslot = tid & 15;   // 0..15 -> out col = pslot + 16*p (tile-local)

    float rsum[4] = {0.f, 0.f, 0.f, 0.f};

    #pragma unroll 1
    for (int pgb = 0; pgb < 2; ++pgb) {      // output rows r = pgb*4 + q
        float acc[4][4][2];
        #pragma unroll
        for (int g = 0; g < 4; ++g)
            #pragma unroll
            for (int q = 0; q < 4; ++q)
                #pragma unroll
                for (int p = 0; p < 2; ++p) acc[g][q][p] = 0.f;

        #pragma unroll 1
        for (int ky = 0; ky < 7; ++ky) {     // unroll 1: keep only 7 wk live
            float4 wk[7];
            #pragma unroll
            for (int kx = 0; kx < 7; ++kx)
                wk[kx] = *(const float4*)&wshT[(ky * 7 + kx) * 64 + (gf4 << 2)];
            #pragma unroll
            for (int q = 0; q < 4; ++q) {
                const int row = (pgb * 4 + q) * 4 + ky;
                #pragma unroll
                for (int p = 0; p < 2; ++p) {
                    const float* xr = &xs[row * 132 + (pslot << 2) + (p << 6)];
                    const float4 xa = *(const float4*)xr;
                    const float4 xb4 = *(const float4*)(xr + 4);
                    const float xv[7] = {xa.x, xa.y, xa.z, xa.w, xb4.x, xb4.y, xb4.z};
                    #pragma unroll
                    for (int kx = 0; kx < 7; ++kx) {
                        acc[0][q][p] += wk[kx].x * xv[kx];
                        acc[1][q][p] += wk[kx].y * xv[kx];
                        acc[2][q][p] += wk[kx].z * xv[kx];
                        acc[3][q][p] += wk[kx].w * xv[kx];
                    }
                }
            }
        }
        #pragma unroll
        for (int g = 0; g < 4; ++g)
            #pragma unroll
            for (int q = 0; q < 4; ++q)
                #pragma unroll
                for (int p = 0; p < 2; ++p)
                    rsum[g] += fmaxf(acc[g][q][p], 0.f);
    }

    #pragma unroll
    for (int g = 0; g < 4; ++g) {
        float v = rsum[g];
        v += __shfl_xor(v, 8);
        v += __shfl_xor(v, 4);
        v += __shfl_xor(v, 2);
        v += __shfl_xor(v, 1);
        if (pslot == 0)
            partials[((b * 16 + tile) * 64) + (gf4 << 2) + g] = v;
    }
}

// ---------------- Kernel 2: gating finalize (feats -> heads -> weights) --------
__global__ void gate_finalize_kernel(
    const float* __restrict__ partials,
    const float* __restrict__ Wc, const float* __restrict__ bc,
    const float* __restrict__ Wp, const float* __restrict__ bp,
    int* __restrict__ gidx, float* __restrict__ gw)
{
    const int b = threadIdx.x;   // 64 threads
    float f[64];
    #pragma unroll
    for (int g = 0; g < 64; ++g) f[g] = 0.f;
    const float* pb = partials + b * 1024;   // 16 tiles x 64 gf, contiguous
    #pragma unroll
    for (int t = 0; t < 16; ++t)
        #pragma unroll
        for (int g4 = 0; g4 < 16; ++g4) {
            const float4 v = *(const float4*)&pb[t * 64 + (g4 << 2)];
            f[(g4 << 2) + 0] += v.x;
            f[(g4 << 2) + 1] += v.y;
            f[(g4 << 2) + 2] += v.z;
            f[(g4 << 2) + 3] += v.w;
        }
    #pragma unroll
    for (int g = 0; g < 64; ++g) f[g] *= (1.0f / 4096.0f);

    float cl[6], pl[2];
    #pragma unroll
    for (int j = 0; j < 6; ++j) {
        float s = bc[j];
        #pragma unroll
        for (int g = 0; g < 64; ++g) s += f[g] * Wc[j * 64 + g];
        cl[j] = s;
    }
    #pragma unroll
    for (int j = 0; j < 2; ++j) {
        float s = bp[j];
        #pragma unroll
        for (int g = 0; g < 64; ++g) s += f[g] * Wp[j * 64 + g];
        pl[j] = s;
    }
    const float pm = fmaxf(pl[0], pl[1]);
    const float e0 = expf(pl[0] - pm), e1 = expf(pl[1] - pm);
    const int   pi = (pl[1] > pl[0]) ? 1 : 0;
    const float pv = fmaxf(e0, e1) / (e0 + e1);
    float cm = cl[0];
    #pragma unroll
    for (int j = 1; j < 6; ++j) cm = fmaxf(cm, cl[j]);
    float es = 0.f, ce[6];
    #pragma unroll
    for (int j = 0; j < 6; ++j) { ce[j] = expf(cl[j] - cm); es += ce[j]; }
    int ci = 0; float cbest = cl[0];
    #pragma unroll
    for (int j = 1; j < 6; ++j) if (cl[j] > cbest) { cbest = cl[j]; ci = j; }
    const float cv = ce[ci] / es;

    const float wp = 0.3f * pv;
    const float wc = 0.7f * cv;
    const float tot = wp + wc + 1e-8f;
    gidx[b]      = pi;
    gidx[64 + b] = ci + 2;
    gw[b]        = wp / tot;
    gw[64 + b]   = wc / tot;
}

// ---------------- Kernel 3: fused two-expert conv3x3 -> relu -> conv3x3 -------
// grid (64 tiles of 32x32, 64 batch), 256 threads
__global__ __launch_bounds__(256) void expert_kernel(
    const float* __restrict__ x,
    const float* __restrict__ We1, const float* __restrict__ be1,
    const float* __restrict__ We2, const float* __restrict__ be2,
    const int* __restrict__ gidx, const float* __restrict__ gw,
    float* __restrict__ out)
{
    __shared__ float xs[36 * 40];                       // fp32 x tile + halo2
    __shared__ __align__(16) unsigned short hs[8 * 34 * 36];  // bf16 h tile + halo1

    const int tile = blockIdx.x;
    const int b    = blockIdx.y;
    const int ty = tile >> 3, tx = tile & 7;
    const int y0 = ty * 32, x0 = tx * 32;
    const int tid = threadIdx.x;
    const bool interior = (ty != 0) && (ty != 7) && (tx != 0) && (tx != 7);

    const float* xb = x + (size_t)b * (IMG * IMG);
    if (interior) {
        for (int i = tid; i < 36 * 40; i += 256) {
            int r = i / 40, c = i - r * 40;
            xs[i] = xb[(y0 - 2 + r) * IMG + (x0 - 2 + c)];
        }
    } else {
        for (int i = tid; i < 36 * 40; i += 256) {
            int r = i / 40, c = i - r * 40;
            float v = 0.f;
            if (c < 36) {
                int gy = y0 - 2 + r, gx = x0 - 2 + c;
                if (gy >= 0 && gy < IMG && gx >= 0 && gx < IMG) v = xb[gy * IMG + gx];
            }
            xs[i] = v;
        }
    }

    const int ep = __builtin_amdgcn_readfirstlane(gidx[b]);
    const int ec = __builtin_amdgcn_readfirstlane(gidx[64 + b]);
    const float wA = __uint_as_float(__builtin_amdgcn_readfirstlane(__float_as_uint(gw[b])));
    const float wB = __uint_as_float(__builtin_amdgcn_readfirstlane(__float_as_uint(gw[64 + b])));

    const int r_ = tid >> 3;          // 0..31 output row
    const int c0 = (tid & 7) << 2;    // output col group (4 cols)
    const int c1ch   = tid >> 5;      // conv1: channel 0..7
    const int lane32 = tid & 31;

    float oacc0 = 0.f, oacc1 = 0.f, oacc2 = 0.f, oacc3 = 0.f;

    __syncthreads();

    for (int ei = 0; ei < 2; ++ei) {
        const int   e   = ei ? ec : ep;
        const float wgt = ei ? wB : wA;

        float w1r[9];
        const float* w1p = We1 + e * 72 + c1ch * 9;
        #pragma unroll
        for (int k = 0; k < 9; ++k) w1r[k] = w1p[k];
        const float b1r = be1[e * 8 + c1ch];

        if (ei) __syncthreads();   // prev conv2 reads done before hs overwrite

        // ---- conv1: h = relu(conv(x) + b1) in bf16, zero outside image ----
        if (interior) {
            for (int j = lane32; j < 306; j += 32) {
                const int hy = j / 9;
                const int cb = (j - hy * 9) << 2;     // 0,4,...,32
                float a0 = b1r, a1 = b1r, a2 = b1r, a3 = b1r;
                #pragma unroll
                for (int ky = 0; ky < 3; ++ky) {
                    const float* xr = &xs[(hy + ky) * 40 + cb];
                    const float2 xa  = *(const float2*)(xr);
                    const float2 xb2 = *(const float2*)(xr + 2);
                    const float2 xc2 = *(const float2*)(xr + 4);
                    const float wa = w1r[ky * 3 + 0], wb = w1r[ky * 3 + 1], wcc = w1r[ky * 3 + 2];
                    a0 += wa * xa.x  + wb * xa.y  + wcc * xb2.x;
                    a1 += wa * xa.y  + wb * xb2.x + wcc * xb2.y;
                    a2 += wa * xb2.x + wb * xb2.y + wcc * xc2.x;
                    a3 += wa * xb2.y + wb * xc2.x + wcc * xc2.y;
                }
                const unsigned int lo = bf16u(fmaxf(a0, 0.f)) | (bf16u(fmaxf(a1, 0.f)) << 16);
                const unsigned int hi = bf16u(fmaxf(a2, 0.f)) | (bf16u(fmaxf(a3, 0.f)) << 16);
                unsigned short* hp = &hs[c1ch * 1224 + hy * 36 + cb];
                if (cb < 32) *(uint2*)hp = make_uint2(lo, hi);
                else         *(unsigned int*)hp = lo;
            }
        } else {
            for (int j = lane32; j < 306; j += 32) {
                const int hy = j / 9;
                const int cb = (j - hy * 9) << 2;
                float a0 = b1r, a1 = b1r, a2 = b1r, a3 = b1r;
                #pragma unroll
                for (int ky = 0; ky < 3; ++ky) {
                    const float* xr = &xs[(hy + ky) * 40 + cb];
                    const float2 xa  = *(const float2*)(xr);
                    const float2 xb2 = *(const float2*)(xr + 2);
                    const float2 xc2 = *(const float2*)(xr + 4);
                    const float wa = w1r[ky * 3 + 0], wb = w1r[ky * 3 + 1], wcc = w1r[ky * 3 + 2];
                    a0 += wa * xa.x  + wb * xa.y  + wcc * xb2.x;
                    a1 += wa * xa.y  + wb * xb2.x + wcc * xb2.y;
                    a2 += wa * xb2.x + wb * xb2.y + wcc * xc2.x;
                    a3 += wa * xb2.y + wb * xc2.x + wcc * xc2.y;
                }
                const int gy = y0 - 1 + hy;
                const int gx = x0 - 1 + cb;
                const bool rowok = (gy >= 0) && (gy < IMG);
                const float h0 = (rowok && gx >= 0 && gx < IMG) ? fmaxf(a0, 0.f) : 0.f;
                const float h1 = (rowok && (gx + 1) < IMG)      ? fmaxf(a1, 0.f) : 0.f;
                const float h2 = (rowok && (gx + 2) < IMG)      ? fmaxf(a2, 0.f) : 0.f;
                const float h3 = (rowok && (gx + 3) < IMG)      ? fmaxf(a3, 0.f) : 0.f;
                const unsigned int lo = bf16u(h0) | (bf16u(h1) << 16);
                const unsigned int hi = bf16u(h2) | (bf16u(h3) << 16);
                unsigned short* hp = &hs[c1ch * 1224 + hy * 36 + cb];
                if (cb < 32) *(uint2*)hp = make_uint2(lo, hi);
                else         *(unsigned int*)hp = lo;
            }
        }
        __syncthreads();

        // ---- conv2: y = conv(h) + b2, accumulate with gate weight ----
        float a0 = 0.f, a1 = 0.f, a2 = 0.f, a3 = 0.f;
        #pragma unroll
        for (int ch = 0; ch < 8; ++ch) {
            const float* w2p = We2 + e * 72 + ch * 9;   // e uniform -> s_load
            float w2r[9];
            #pragma unroll
            for (int k = 0; k < 9; ++k) w2r[k] = w2p[k];
            #pragma unroll
            for (int ky = 0; ky < 3; ++ky) {
                const unsigned short* hp = &hs[ch * 1224 + (r_ + ky) * 36 + c0];
                const uint2 q4 = *(const uint2*)hp;
                const unsigned int q2 = *(const unsigned int*)(hp + 4);
                const float h0 = bflo(q4.x), h1 = bfhi(q4.x);
                const float h2 = bflo(q4.y), h3 = bfhi(q4.y);
                const float h4 = bflo(q2),   h5 = bfhi(q2);
                const float wa = w2r[ky * 3], wb = w2r[ky * 3 + 1], wcx = w2r[ky * 3 + 2];
                a0 += wa * h0 + wb * h1 + wcx * h2;
                a1 += wa * h1 + wb * h2 + wcx * h3;
                a2 += wa * h2 + wb * h3 + wcx * h4;
                a3 += wa * h3 + wb * h4 + wcx * h5;
            }
        }
        const float b2v = be2[e];
        oacc0 += wgt * (a0 + b2v);
        oacc1 += wgt * (a1 + b2v);
        oacc2 += wgt * (a2 + b2v);
        oacc3 += wgt * (a3 + b2v);
    }

    const float4 o4 = make_float4(oacc0, oacc1, oacc2, oacc3);
    *(float4*)&out[(size_t)b * (IMG * IMG) + (y0 + r_) * IMG + (x0 + c0)] = o4;
}

extern "C" void kernel_launch(void* const* d_in, const int* in_sizes, int n_in,
                              void* d_out, int out_size, void* d_ws, size_t ws_size,
                              hipStream_t stream) {
    const float* x   = (const float*)d_in[0];
    const float* Wg  = (const float*)d_in[1];
    const float* Wc  = (const float*)d_in[2];
    const float* bc  = (const float*)d_in[3];
    const float* Wp  = (const float*)d_in[4];
    const float* bp  = (const float*)d_in[5];
    const float* We1 = (const float*)d_in[6];
    const float* be1 = (const float*)d_in[7];
    const float* We2 = (const float*)d_in[8];
    const float* be2 = (const float*)d_in[9];
    float* out = (float*)d_out;

    float* partials = (float*)d_ws;                              // 64*16*64 floats = 256 KB
    int*   gidx     = (int*)((char*)d_ws + 262144);              // 128 ints
    float* gw       = (float*)((char*)d_ws + 262144 + 512);      // 128 floats

    gate_conv_kernel<<<dim3(16, 64), dim3(256), 0, stream>>>(x, Wg, partials);
    gate_finalize_kernel<<<dim3(1), dim3(64), 0, stream>>>(partials, Wc, bc, Wp, bp, gidx, gw);
    expert_kernel<<<dim3(64, 64), dim3(256), 0, stream>>>(x, We1, be1, We2, be2, gidx, gw, out);
}

// Round 4
// 114.720 us; speedup vs baseline: 4.2875x; 1.1300x over previous
//
#include <hip/hip_runtime.h>
#include <hip/hip_bf16.h>
#include <math.h>

#define IMG 256

typedef __attribute__((ext_vector_type(4))) short short4v;
typedef __attribute__((ext_vector_type(8))) short short8v;
typedef __attribute__((ext_vector_type(4))) float f32x4;

__device__ __forceinline__ short bf16s(float f) {
    __hip_bfloat16 h = __float2bfloat16(f);
    short s; __builtin_memcpy(&s, &h, 2); return s;
}
__device__ __forceinline__ unsigned int bf16u(float f) {
    return (unsigned int)(unsigned short)bf16s(f);
}
__device__ __forceinline__ float bflo(unsigned int v) { return __uint_as_float(v << 16); }
__device__ __forceinline__ float bfhi(unsigned int v) { return __uint_as_float(v & 0xffff0000u); }

// ---------------- Kernel 1: gating conv 7x7 s4 + relu + partial sums via MFMA --
// GEMM view: M = out pixels (8 rows x 64 cols per block), N = 64 gf, K = 49->64
// k-order: k = ky*8 + kx  (kx 0..6 real, kx==7 zero pad; ky 0..6 real, 7 pad)
// W split into bf16 hi+lo (systematic rounding error ~2^-18); x single bf16.
// grid (8 row-tiles, 64 batch), 256 threads
__global__ __launch_bounds__(256) void gate_mfma_kernel(
    const float* __restrict__ x, const float* __restrict__ Wg,
    float* __restrict__ partials)
{
    __shared__ short xs[36 * 264];     // x rows 32rt-1..+34, cols -1..258 (+1 off)
    __shared__ short whi[64 * 66];     // [k][gf], stride 66 = conflict-free build
    __shared__ short wlo[64 * 66];
    __shared__ float red[4][64];

    const int rt  = blockIdx.x;        // 0..7
    const int b   = blockIdx.y;
    const int tid = threadIdx.x;

    for (int i = tid; i < 64 * 64; i += 256) {
        const int k = i >> 6, gf = i & 63;
        const int ky = k >> 3, kx = k & 7;
        float wv = 0.f;
        if (kx < 7 && ky < 7) wv = Wg[gf * 49 + ky * 7 + kx];
        const short hi = bf16s(wv);
        const float hif = __uint_as_float(((unsigned int)(unsigned short)hi) << 16);
        whi[k * 66 + gf] = hi;
        wlo[k * 66 + gf] = bf16s(wv - hif);
    }
    const float* xb = x + (size_t)b * (IMG * IMG);
    const int gy0 = rt * 32 - 1;
    for (int i = tid; i < 36 * 260; i += 256) {
        const int r = i / 260, c = i - r * 260;
        const int gy = gy0 + r, gx = c - 1;
        float v = 0.f;
        if (gy >= 0 && gy < IMG && gx >= 0 && gx < IMG) v = xb[gy * IMG + gx];
        xs[r * 264 + c] = bf16s(v);
    }
    __syncthreads();

    const int lane = tid & 63;
    const int wv_  = tid >> 6;   // wave 0..3
    const int m    = lane & 15;  // A: pixel row; B/D: column (gf)
    const int kb   = lane >> 4;  // k-group 0..3

    // B frags: lane holds B[k=(kb+4s)*8+j][nc*16+m]
    short8v Bhi[2][4], Blo[2][4];
    #pragma unroll
    for (int s = 0; s < 2; ++s) {
        const int kbg = kb + 4 * s;
        #pragma unroll
        for (int nc = 0; nc < 4; ++nc) {
            short8v bh, bl;
            #pragma unroll
            for (int j = 0; j < 8; ++j) {
                bh[j] = whi[(kbg * 8 + j) * 66 + nc * 16 + m];
                bl[j] = wlo[(kbg * 8 + j) * 66 + nc * 16 + m];
            }
            Bhi[s][nc] = bh; Blo[s][nc] = bl;
        }
    }

    float rsum[4] = {0.f, 0.f, 0.f, 0.f};
    const f32x4 zero4 = {0.f, 0.f, 0.f, 0.f};

    #pragma unroll 1
    for (int i = 0; i < 8; ++i) {             // 8 chunks per wave, 32 per block
        const int chunk = wv_ * 8 + i;
        const int r = chunk >> 2, q = chunk & 3;   // out row r, col group 16q
        // A[m][k=(kb+4s)*8+j] = x[4r-1+(kb+4s)][(64q+4m+j)-1] -> xs[4r+ky][64q+4m+j]
        short8v A[2];
        #pragma unroll
        for (int s = 0; s < 2; ++s) {
            const int row = 4 * r + kb + 4 * s;
            const short4v* p = (const short4v*)&xs[row * 264 + 64 * q + 4 * m];
            const short4v lo4 = p[0], hi4 = p[1];
            A[s] = __builtin_shufflevector(lo4, hi4, 0, 1, 2, 3, 4, 5, 6, 7);
        }
        #pragma unroll
        for (int nc = 0; nc < 4; ++nc) {
            f32x4 z = __builtin_amdgcn_mfma_f32_16x16x32_bf16(A[0], Bhi[0][nc], zero4, 0, 0, 0);
            z = __builtin_amdgcn_mfma_f32_16x16x32_bf16(A[1], Bhi[1][nc], z, 0, 0, 0);
            z = __builtin_amdgcn_mfma_f32_16x16x32_bf16(A[0], Blo[0][nc], z, 0, 0, 0);
            z = __builtin_amdgcn_mfma_f32_16x16x32_bf16(A[1], Blo[1][nc], z, 0, 0, 0);
            rsum[nc] += fmaxf(z[0], 0.f) + fmaxf(z[1], 0.f) + fmaxf(z[2], 0.f) + fmaxf(z[3], 0.f);
        }
    }

    // sum across the 4 kb lane-groups (bits 4,5); col n = lane&15 is gf%16
    #pragma unroll
    for (int nc = 0; nc < 4; ++nc) {
        float v = rsum[nc];
        v += __shfl_xor(v, 16);
        v += __shfl_xor(v, 32);
        if (lane < 16) red[wv_][nc * 16 + lane] = v;
    }
    __syncthreads();
    if (tid < 64) {
        const float s = red[0][tid] + red[1][tid] + red[2][tid] + red[3][tid];
        partials[(b * 8 + rt) * 64 + tid] = s;
    }
}

// ---------------- Kernel 2: gating finalize (feats -> heads -> weights) --------
__global__ void gate_finalize_kernel(
    const float* __restrict__ partials,
    const float* __restrict__ Wc, const float* __restrict__ bc,
    const float* __restrict__ Wp, const float* __restrict__ bp,
    int* __restrict__ gidx, float* __restrict__ gw)
{
    const int b = threadIdx.x;   // 64 threads
    float f[64];
    #pragma unroll
    for (int g = 0; g < 64; ++g) f[g] = 0.f;
    const float* pb = partials + b * 512;   // 8 tiles x 64 gf
    #pragma unroll
    for (int t = 0; t < 8; ++t)
        #pragma unroll
        for (int g4 = 0; g4 < 16; ++g4) {
            const float4 v = *(const float4*)&pb[t * 64 + (g4 << 2)];
            f[(g4 << 2) + 0] += v.x;
            f[(g4 << 2) + 1] += v.y;
            f[(g4 << 2) + 2] += v.z;
            f[(g4 << 2) + 3] += v.w;
        }
    #pragma unroll
    for (int g = 0; g < 64; ++g) f[g] *= (1.0f / 4096.0f);

    float cl[6], pl[2];
    #pragma unroll
    for (int j = 0; j < 6; ++j) {
        float s = bc[j];
        #pragma unroll
        for (int g = 0; g < 64; ++g) s += f[g] * Wc[j * 64 + g];
        cl[j] = s;
    }
    #pragma unroll
    for (int j = 0; j < 2; ++j) {
        float s = bp[j];
        #pragma unroll
        for (int g = 0; g < 64; ++g) s += f[g] * Wp[j * 64 + g];
        pl[j] = s;
    }
    const float pm = fmaxf(pl[0], pl[1]);
    const float e0 = expf(pl[0] - pm), e1 = expf(pl[1] - pm);
    const int   pi = (pl[1] > pl[0]) ? 1 : 0;
    const float pv = fmaxf(e0, e1) / (e0 + e1);
    float cm = cl[0];
    #pragma unroll
    for (int j = 1; j < 6; ++j) cm = fmaxf(cm, cl[j]);
    float es = 0.f, ce[6];
    #pragma unroll
    for (int j = 0; j < 6; ++j) { ce[j] = expf(cl[j] - cm); es += ce[j]; }
    int ci = 0; float cbest = cl[0];
    #pragma unroll
    for (int j = 1; j < 6; ++j) if (cl[j] > cbest) { cbest = cl[j]; ci = j; }
    const float cv = ce[ci] / es;

    const float wp = 0.3f * pv;
    const float wc = 0.7f * cv;
    const float tot = wp + wc + 1e-8f;
    gidx[b]      = pi;
    gidx[64 + b] = ci + 2;
    gw[b]        = wp / tot;
    gw[64 + b]   = wc / tot;
}

// ---------------- Kernel 3: fused two-expert conv3x3 -> relu -> conv3x3 -------
// grid (64 tiles of 32x32, 64 batch), 256 threads. hs row stride 40 shorts
// (20 banks: row bases {0,20,8,28,16,4,24,12} -> conv2 b64 reads structural-only)
__global__ __launch_bounds__(256) void expert_kernel(
    const float* __restrict__ x,
    const float* __restrict__ We1, const float* __restrict__ be1,
    const float* __restrict__ We2, const float* __restrict__ be2,
    const int* __restrict__ gidx, const float* __restrict__ gw,
    float* __restrict__ out)
{
    __shared__ float xs[36 * 40];                             // fp32 x tile + halo2
    __shared__ __align__(16) unsigned short hs[8 * 34 * 40];  // bf16 h, stride 40

    const int tile = blockIdx.x;
    const int b    = blockIdx.y;
    const int ty = tile >> 3, tx = tile & 7;
    const int y0 = ty * 32, x0 = tx * 32;
    const int tid = threadIdx.x;
    const bool interior = (ty != 0) && (ty != 7) && (tx != 0) && (tx != 7);

    const float* xb = x + (size_t)b * (IMG * IMG);
    if (interior) {
        for (int i = tid; i < 36 * 40; i += 256) {
            int r = i / 40, c = i - r * 40;
            xs[i] = xb[(y0 - 2 + r) * IMG + (x0 - 2 + c)];
        }
    } else {
        for (int i = tid; i < 36 * 40; i += 256) {
            int r = i / 40, c = i - r * 40;
            float v = 0.f;
            if (c < 36) {
                int gy = y0 - 2 + r, gx = x0 - 2 + c;
                if (gy >= 0 && gy < IMG && gx >= 0 && gx < IMG) v = xb[gy * IMG + gx];
            }
            xs[i] = v;
        }
    }

    const int ep = __builtin_amdgcn_readfirstlane(gidx[b]);
    const int ec = __builtin_amdgcn_readfirstlane(gidx[64 + b]);
    const float wA = __uint_as_float(__builtin_amdgcn_readfirstlane(__float_as_uint(gw[b])));
    const float wB = __uint_as_float(__builtin_amdgcn_readfirstlane(__float_as_uint(gw[64 + b])));

    const int r_ = tid >> 3;          // 0..31 output row
    const int c0 = (tid & 7) << 2;    // output col group (4 cols)
    const int c1ch   = tid >> 5;      // conv1: channel 0..7
    const int lane32 = tid & 31;

    float oacc0 = 0.f, oacc1 = 0.f, oacc2 = 0.f, oacc3 = 0.f;

    __syncthreads();

    for (int ei = 0; ei < 2; ++ei) {
        const int   e   = ei ? ec : ep;
        const float wgt = ei ? wB : wA;

        float w1r[9];
        const float* w1p = We1 + e * 72 + c1ch * 9;
        #pragma unroll
        for (int k = 0; k < 9; ++k) w1r[k] = w1p[k];
        const float b1r = be1[e * 8 + c1ch];

        if (ei) __syncthreads();   // prev conv2 reads done before hs overwrite

        // ---- conv1: h = relu(conv(x) + b1) in bf16, zero outside image ----
        if (interior) {
            for (int j = lane32; j < 306; j += 32) {
                const int hy = j / 9;
                const int cb = (j - hy * 9) << 2;     // 0,4,...,32
                float a0 = b1r, a1 = b1r, a2 = b1r, a3 = b1r;
                #pragma unroll
                for (int ky = 0; ky < 3; ++ky) {
                    const float* xr = &xs[(hy + ky) * 40 + cb];
                    const float2 xa  = *(const float2*)(xr);
                    const float2 xb2 = *(const float2*)(xr + 2);
                    const float2 xc2 = *(const float2*)(xr + 4);
                    const float wa = w1r[ky * 3 + 0], wb = w1r[ky * 3 + 1], wcc = w1r[ky * 3 + 2];
                    a0 += wa * xa.x  + wb * xa.y  + wcc * xb2.x;
                    a1 += wa * xa.y  + wb * xb2.x + wcc * xb2.y;
                    a2 += wa * xb2.x + wb * xb2.y + wcc * xc2.x;
                    a3 += wa * xb2.y + wb * xc2.x + wcc * xc2.y;
                }
                const unsigned int lo = bf16u(fmaxf(a0, 0.f)) | (bf16u(fmaxf(a1, 0.f)) << 16);
                const unsigned int hi = bf16u(fmaxf(a2, 0.f)) | (bf16u(fmaxf(a3, 0.f)) << 16);
                unsigned short* hp = &hs[c1ch * 1360 + hy * 40 + cb];
                if (cb < 32) *(uint2*)hp = make_uint2(lo, hi);
                else         *(unsigned int*)hp = lo;
            }
        } else {
            for (int j = lane32; j < 306; j += 32) {
                const int hy = j / 9;
                const int cb = (j - hy * 9) << 2;
                float a0 = b1r, a1 = b1r, a2 = b1r, a3 = b1r;
                #pragma unroll
                for (int ky = 0; ky < 3; ++ky) {
                    const float* xr = &xs[(hy + ky) * 40 + cb];
                    const float2 xa  = *(const float2*)(xr);
                    const float2 xb2 = *(const float2*)(xr + 2);
                    const float2 xc2 = *(const float2*)(xr + 4);
                    const float wa = w1r[ky * 3 + 0], wb = w1r[ky * 3 + 1], wcc = w1r[ky * 3 + 2];
                    a0 += wa * xa.x  + wb * xa.y  + wcc * xb2.x;
                    a1 += wa * xa.y  + wb * xb2.x + wcc * xb2.y;
                    a2 += wa * xb2.x + wb * xb2.y + wcc * xc2.x;
                    a3 += wa * xb2.y + wb * xc2.x + wcc * xc2.y;
                }
                const int gy = y0 - 1 + hy;
                const int gx = x0 - 1 + cb;
                const bool rowok = (gy >= 0) && (gy < IMG);
                const float h0 = (rowok && gx >= 0 && gx < IMG) ? fmaxf(a0, 0.f) : 0.f;
                const float h1 = (rowok && (gx + 1) < IMG)      ? fmaxf(a1, 0.f) : 0.f;
                const float h2 = (rowok && (gx + 2) < IMG)      ? fmaxf(a2, 0.f) : 0.f;
                const float h3 = (rowok && (gx + 3) < IMG)      ? fmaxf(a3, 0.f) : 0.f;
                const unsigned int lo = bf16u(h0) | (bf16u(h1) << 16);
                const unsigned int hi = bf16u(h2) | (bf16u(h3) << 16);
                unsigned short* hp = &hs[c1ch * 1360 + hy * 40 + cb];
                if (cb < 32) *(uint2*)hp = make_uint2(lo, hi);
                else         *(unsigned int*)hp = lo;
            }
        }
        __syncthreads();

        // ---- conv2: y = conv(h) + b2, accumulate with gate weight ----
        float a0 = 0.f, a1 = 0.f, a2 = 0.f, a3 = 0.f;
        #pragma unroll
        for (int ch = 0; ch < 8; ++ch) {
            const float* w2p = We2 + e * 72 + ch * 9;   // e uniform -> s_load
            float w2r[9];
            #pragma unroll
            for (int k = 0; k < 9; ++k) w2r[k] = w2p[k];
            #pragma unroll
            for (int ky = 0; ky < 3; ++ky) {
                const unsigned short* hp = &hs[ch * 1360 + (r_ + ky) * 40 + c0];
                const uint2 q4 = *(const uint2*)hp;
                const unsigned int q2 = *(const unsigned int*)(hp + 4);
                const float h0 = bflo(q4.x), h1 = bfhi(q4.x);
                const float h2 = bflo(q4.y), h3 = bfhi(q4.y);
                const float h4 = bflo(q2),   h5 = bfhi(q2);
                const float wa = w2r[ky * 3], wb = w2r[ky * 3 + 1], wcx = w2r[ky * 3 + 2];
                a0 += wa * h0 + wb * h1 + wcx * h2;
                a1 += wa * h1 + wb * h2 + wcx * h3;
                a2 += wa * h2 + wb * h3 + wcx * h4;
                a3 += wa * h3 + wb * h4 + wcx * h5;
            }
        }
        const float b2v = be2[e];
        oacc0 += wgt * (a0 + b2v);
        oacc1 += wgt * (a1 + b2v);
        oacc2 += wgt * (a2 + b2v);
        oacc3 += wgt * (a3 + b2v);
    }

    const float4 o4 = make_float4(oacc0, oacc1, oacc2, oacc3);
    *(float4*)&out[(size_t)b * (IMG * IMG) + (y0 + r_) * IMG + (x0 + c0)] = o4;
}

extern "C" void kernel_launch(void* const* d_in, const int* in_sizes, int n_in,
                              void* d_out, int out_size, void* d_ws, size_t ws_size,
                              hipStream_t stream) {
    const float* x   = (const float*)d_in[0];
    const float* Wg  = (const float*)d_in[1];
    const float* Wc  = (const float*)d_in[2];
    const float* bc  = (const float*)d_in[3];
    const float* Wp  = (const float*)d_in[4];
    const float* bp  = (const float*)d_in[5];
    const float* We1 = (const float*)d_in[6];
    const float* be1 = (const float*)d_in[7];
    const float* We2 = (const float*)d_in[8];
    const float* be2 = (const float*)d_in[9];
    float* out = (float*)d_out;

    float* partials = (float*)d_ws;                              // 64*8*64 floats = 128 KB
    int*   gidx     = (int*)((char*)d_ws + 131072);              // 128 ints
    float* gw       = (float*)((char*)d_ws + 131072 + 512);      // 128 floats

    gate_mfma_kernel<<<dim3(8, 64), dim3(256), 0, stream>>>(x, Wg, partials);
    gate_finalize_kernel<<<dim3(1), dim3(64), 0, stream>>>(partials, Wc, bc, Wp, bp, gidx, gw);
    expert_kernel<<<dim3(64, 64), dim3(256), 0, stream>>>(x, We1, be1, We2, be2, gidx, gw, out);
}